// Round 10
// baseline (133.716 us; speedup 1.0000x reference)
//
#include <hip/hip_runtime.h>
#include <hip/hip_bf16.h>

// R10 = R9 minus the cvt dispatch: GEMMs stage fp32 A/B with inline RNE->bf16
// conversion and plain ushort8 LDS stores (R3/R4 measured this ≈ DMA staging for
// this K=384 regime), single-barrier double-buffered pipeline kept. Attn unchanged
// from R9 (DMA dbuf + XCD slab swizzle, S^T trick + mfma16 PV).
//   gemm<0,256>@512thr: x fp32 -> qg bf16 row-major (q pre-scaled 0.125),
//                       K/V in MFMA-operand-order slabs per (b,h).
//   attn @768x256:      dbuf LDS staging, no fences, R5-validated lane mappings.
//   gemm<1,128>@256thr: aout bf16 @ w_proj fp32 -> out fp32.
// ws (ushort elems): qg 3145728 | kg 3145728 | vg 3145728 | aout 3145728 => 25.2 MB.

typedef __attribute__((__ext_vector_type__(8))) __bf16 bf16x8;
typedef __attribute__((__ext_vector_type__(8))) unsigned short ushort8;
typedef __attribute__((__ext_vector_type__(4))) unsigned short ushort4v;
typedef __attribute__((__ext_vector_type__(4))) short short4v;
typedef __attribute__((__ext_vector_type__(4))) float f32x4;

#define NX 3145728   // 8192*384

__device__ __forceinline__ f32x4 mfma32(bf16x8 a, bf16x8 b, f32x4 c) {
    return __builtin_amdgcn_mfma_f32_16x16x32_bf16(a, b, c, 0, 0, 0);
}
__device__ __forceinline__ f32x4 mfma16(short4v a, short4v b, f32x4 c) {
    return __builtin_amdgcn_mfma_f32_16x16x16bf16_1k(a, b, c, 0, 0, 0);
}

__device__ __forceinline__ unsigned short f2bf(float f) {
    union { float f; unsigned int i; } x; x.f = f;
    unsigned int u = x.i;
    return (unsigned short)((u + 0x7fffu + ((u >> 16) & 1u)) >> 16);
}

// Load 8 consecutive elements as bf16 (converting when fp32).
__device__ __forceinline__ ushort8 load8_bf16(const float* p) {
    float4 a = *(const float4*)p;
    float4 b = *(const float4*)(p + 4);
    ushort8 r;
    r[0] = f2bf(a.x); r[1] = f2bf(a.y); r[2] = f2bf(a.z); r[3] = f2bf(a.w);
    r[4] = f2bf(b.x); r[5] = f2bf(b.y); r[6] = f2bf(b.z); r[7] = f2bf(b.w);
    return r;
}
__device__ __forceinline__ ushort8 load8_bf16(const unsigned short* p) {
    return *(const ushort8*)p;
}

__device__ __forceinline__ void dma16(const unsigned short* g, unsigned short* l) {
    __builtin_amdgcn_global_load_lds(
        (const __attribute__((address_space(1))) unsigned int*)g,
        (__attribute__((address_space(3))) unsigned int*)l, 16, 0, 0);
}

// C = A[M,K] @ B[N,K]^T + bias. TA in {float, ushort/bf16}, B fp32 (inline cvt).
// fp32 acc, TMx128 tile, BK=32, THREADS=2*TM. Single-barrier dbuf pipeline:
// iter c: barrier -> stage(c+1) into buf (c+1)&1 -> compute(c) from buf c&1.
// stage(c+1) writes the buffer compute(c-1) read; the barrier separates them.
// MODE 0 (QKV): n<384 -> qg row-major *0.125 ; 384..768 -> kg operand-order ; >=768 -> vg.
//   kg slab (b,h) [64 kt][2 half][4 quad][16 l15][8 j]: K[kv=kt*16+l15][c=half*32+quad*8+j]
//   vg slab (b,h) [16 c][4 jt][4 dt][4 quad][16 l15][4 j]: V^T[d=dt*16+l15][kv=c*64+jt*16+quad*4+j]
// MODE 1 (proj): fp32 out + bias.
template <int MODE, int TM, typename TA>
__global__ __launch_bounds__(TM * 2) void gemm_bt(
    const TA* __restrict__ A,
    const float* __restrict__ B,
    const float* __restrict__ bias,
    unsigned short* __restrict__ qg,
    unsigned short* __restrict__ kg,
    unsigned short* __restrict__ vg,
    float* __restrict__ out,
    int M, int N, int K)
{
    const int tid  = threadIdx.x;
    const int lane = tid & 63;
    const int wave = tid >> 6;
    const int l15  = lane & 15;
    const int quad = lane >> 4;
    const int m0 = blockIdx.x * TM;
    const int n0 = blockIdx.y * 128;
    const int wm = (wave >> 1) * 64;
    const int wn = (wave & 1) * 64;

    __shared__ __align__(16) unsigned short As[2 * TM * 32];
    __shared__ __align__(16) unsigned short Bs[2 * 128 * 32];

    f32x4 acc[4][4];
    #pragma unroll
    for (int i = 0; i < 4; ++i)
        #pragma unroll
        for (int j = 0; j < 4; ++j)
            acc[i][j] = (f32x4){0.f, 0.f, 0.f, 0.f};

    // stage K-slice k0 into buffer buf (plain vector stores, inline cvt for fp32)
    auto stage = [&](int k0, int buf) {
        #pragma unroll
        for (int t = 0; t < 2; ++t) {
            int i = tid + t * TM * 2;
            *(ushort8*)(As + buf * TM * 32 + i * 8) =
                load8_bf16(A + (size_t)(m0 + (i >> 2)) * K + k0 + (i & 3) * 8);
        }
        #pragma unroll
        for (int t = 0; t < 512 / (TM * 2); ++t) {
            int i = tid + t * TM * 2;
            *(ushort8*)(Bs + buf * 4096 + i * 8) =
                load8_bf16(B + (size_t)(n0 + (i >> 2)) * K + k0 + (i & 3) * 8);
        }
    };

    const int nk = K >> 5;   // 12
    stage(0, 0);
    for (int ki = 0; ki < nk; ++ki) {
        __syncthreads();                       // stage(ki) visible; compute(ki-1) done
        if (ki + 1 < nk) stage((ki + 1) << 5, (ki + 1) & 1);
        const unsigned short* as = As + (ki & 1) * TM * 32;
        const unsigned short* bs = Bs + (ki & 1) * 4096;

        bf16x8 af[4], bff[4];
        #pragma unroll
        for (int mt = 0; mt < 4; ++mt)
            af[mt] = *(const bf16x8*)(as + (wm + mt * 16 + l15) * 32 + quad * 8);
        #pragma unroll
        for (int nt = 0; nt < 4; ++nt)
            bff[nt] = *(const bf16x8*)(bs + (wn + nt * 16 + l15) * 32 + quad * 8);
        #pragma unroll
        for (int mt = 0; mt < 4; ++mt)
            #pragma unroll
            for (int nt = 0; nt < 4; ++nt)
                acc[mt][nt] = mfma32(af[mt], bff[nt], acc[mt][nt]);
    }

    if constexpr (MODE == 0) {
        if (n0 < 384) {            // Q region: row-major, pre-scaled
            #pragma unroll
            for (int nt = 0; nt < 4; ++nt) {
                int n = n0 + wn + nt * 16 + l15;
                float bv = bias[n];
                #pragma unroll
                for (int mt = 0; mt < 4; ++mt) {
                    int mbase = m0 + wm + mt * 16 + quad * 4;
                    #pragma unroll
                    for (int r = 0; r < 4; ++r)
                        qg[(size_t)(mbase + r) * 384 + n] = f2bf((acc[mt][nt][r] + bv) * 0.125f);
                }
            }
        } else if (n0 < 768) {     // K region: operand-order slabs
            #pragma unroll
            for (int nt = 0; nt < 4; ++nt) {
                int n = n0 + wn + nt * 16 + l15;
                float bv = bias[n];
                int c2 = n - 384;
                int h = c2 >> 6, ck = c2 & 63;
                int half = ck >> 5, qd = (ck >> 3) & 3, j = ck & 7;
                #pragma unroll
                for (int mt = 0; mt < 4; ++mt) {
                    int mbase = m0 + wm + mt * 16 + quad * 4;
                    #pragma unroll
                    for (int r = 0; r < 4; ++r) {
                        int tok = mbase + r;
                        int b = tok >> 10, kv = tok & 1023;
                        int kt = kv >> 4, lk = kv & 15;
                        kg[(size_t)(b * 6 + h) * 65536 +
                           ((((size_t)kt * 2 + half) * 4 + qd) * 16 + lk) * 8 + j]
                            = f2bf(acc[mt][nt][r] + bv);
                    }
                }
            }
        } else {                   // V region: operand-order slabs, packed r-contiguous
            #pragma unroll
            for (int nt = 0; nt < 4; ++nt) {
                int n = n0 + wn + nt * 16 + l15;
                float bv = bias[n];
                int c2 = n - 768;
                int h = c2 >> 6, d = c2 & 63;
                int dt = d >> 4, lv = d & 15;
                #pragma unroll
                for (int mt = 0; mt < 4; ++mt) {
                    int mbase = m0 + wm + mt * 16 + quad * 4;   // multiple of 4
                    int b = mbase >> 10, kvb = mbase & 1023;
                    int cc = kvb >> 6, jt = (kvb >> 4) & 3, qd = (kvb >> 2) & 3;
                    ushort4v pk;
                    #pragma unroll
                    for (int r = 0; r < 4; ++r) pk[r] = f2bf(acc[mt][nt][r] + bv);
                    *(ushort4v*)(vg + (size_t)(b * 6 + h) * 65536 + (size_t)cc * 4096 +
                                 (((jt * 4 + dt) * 4 + qd) * 16 + lv) * 4) = pk;
                }
            }
        }
    } else {
        #pragma unroll
        for (int nt = 0; nt < 4; ++nt) {
            int n = n0 + wn + nt * 16 + l15;
            float bv = bias[n];
            #pragma unroll
            for (int mt = 0; mt < 4; ++mt) {
                int mbase = m0 + wm + mt * 16 + quad * 4;
                #pragma unroll
                for (int r = 0; r < 4; ++r)
                    out[(size_t)(mbase + r) * N + n] = acc[mt][nt][r] + bv;
            }
        }
    }
}

// Flash attention, dbuf LDS pipeline + XCD-locality swizzle. Identical to R9.
__global__ __launch_bounds__(256) void attn_fused(
    const unsigned short* __restrict__ qg,
    const unsigned short* __restrict__ kg,
    const unsigned short* __restrict__ vg,
    unsigned short* __restrict__ aout)   // [8192][384] bf16
{
    const int tid  = threadIdx.x;
    const int wave = tid >> 6;
    const int lane = tid & 63;
    const int l15  = lane & 15;
    const int quad = lane >> 4;
    const int id = blockIdx.x;
    const int s  = id % 48;      // slab = b*6+h (pins slab to one XCD: id%8 == s%8)
    const int qt = id / 48;      // 0..15
    const int b  = s / 6;
    const int h  = s % 6;

    const size_t rowbase = (size_t)b * 1024;
    const unsigned short* Kslab = kg + (size_t)s * 65536;
    const unsigned short* Vslab = vg + (size_t)s * 65536;
    const int q0 = qt * 64 + wave * 16;

    __shared__ __align__(16) unsigned short Kb[2 * 4096];
    __shared__ __align__(16) unsigned short Vb[2 * 4096];

    bf16x8 aq0, aq1;
    {
        const unsigned short* qrow = qg + (rowbase + q0 + l15) * 384 + h * 64 + quad * 8;
        aq0 = *(const bf16x8*)qrow;
        aq1 = *(const bf16x8*)(qrow + 32);
    }

    f32x4 accO[4];
    #pragma unroll
    for (int dt = 0; dt < 4; ++dt) accO[dt] = (f32x4){0.f, 0.f, 0.f, 0.f};
    float lsum = 0.f;

    auto stage = [&](int c, int buf) {
        #pragma unroll
        for (int t = 0; t < 2; ++t) {
            int i = tid + t * 256;
            dma16(Kslab + (size_t)c * 4096 + i * 8, Kb + buf * 4096 + t * 2048 + wave * 512);
            dma16(Vslab + (size_t)c * 4096 + i * 8, Vb + buf * 4096 + t * 2048 + wave * 512);
        }
    };

    stage(0, 0);
    for (int c = 0; c < 16; ++c) {
        __syncthreads();                          // drains chunk c's DMA; syncs compute c-1
        if (c + 1 < 16) stage(c + 1, (c + 1) & 1);   // in flight during compute of c
        const unsigned short* kb = Kb + (c & 1) * 4096;
        const unsigned short* vb = Vb + (c & 1) * 4096;

        #pragma unroll
        for (int kt = 0; kt < 4; ++kt) {
            bf16x8 ka  = *(const bf16x8*)(kb + (((kt * 2 + 0) * 4 + quad) * 16 + l15) * 8);
            bf16x8 kbf = *(const bf16x8*)(kb + (((kt * 2 + 1) * 4 + quad) * 16 + l15) * 8);
            f32x4 z = (f32x4){0.f, 0.f, 0.f, 0.f};
            z = mfma32(ka, aq0, z);
            z = mfma32(kbf, aq1, z);   // S^T[kv=quad*4+r][q=l15]

            short4v p;
            #pragma unroll
            for (int r = 0; r < 4; ++r) {
                float sc = z[r];
                sc = (sc < 0.f) ? 0.f : __expf(sc);   // threshold mask -> exact 0 (matches ref)
                lsum += sc;
                p[r] = (short)f2bf(sc);
            }
            #pragma unroll
            for (int dt = 0; dt < 4; ++dt) {
                short4v vv = *(const short4v*)(vb + (((kt * 4 + dt) * 4 + quad) * 16 + l15) * 4);
                accO[dt] = mfma16(vv, p, accO[dt]);
            }
        }
    }

    lsum += __shfl_xor(lsum, 16, 64);
    lsum += __shfl_xor(lsum, 32, 64);
    float inv = 1.0f / lsum;

    unsigned short* orow = aout + (rowbase + q0 + l15) * 384 + h * 64 + quad * 4;
    #pragma unroll
    for (int dt = 0; dt < 4; ++dt) {
        ushort4v pk;
        #pragma unroll
        for (int r = 0; r < 4; ++r) pk[r] = f2bf(accO[dt][r] * inv);
        *(ushort4v*)(orow + dt * 16) = pk;
    }
}

extern "C" void kernel_launch(void* const* d_in, const int* in_sizes, int n_in,
                              void* d_out, int out_size, void* d_ws, size_t ws_size,
                              hipStream_t stream) {
    const float* x      = (const float*)d_in[0];  // [8,1024,384]
    const float* w_qkv  = (const float*)d_in[1];  // [1152,384]
    const float* b_qkv  = (const float*)d_in[2];  // [1152]
    const float* w_proj = (const float*)d_in[3];  // [384,384]
    const float* b_proj = (const float*)d_in[4];  // [384]
    float* out = (float*)d_out;                   // [8,1024,384]

    unsigned short* qg   = (unsigned short*)d_ws;            // 8192*384
    unsigned short* kgp  = qg   + (size_t)NX;                // 48*65536
    unsigned short* vgp  = kgp  + (size_t)NX;                // 48*65536
    unsigned short* aout = vgp  + (size_t)NX;                // 8192*384

    gemm_bt<0, 256, float><<<dim3(32, 9), 512, 0, stream>>>(
        x, w_qkv, b_qkv, qg, kgp, vgp, nullptr, 8192, 1152, 384);
    attn_fused<<<768, 256, 0, stream>>>(qg, kgp, vgp, aout);
    gemm_bt<1, 128, unsigned short><<<dim3(64, 3), 256, 0, stream>>>(
        aout, w_proj, b_proj, nullptr, nullptr, nullptr, out, 8192, 384, 384);
}

// Round 11
// 129.494 us; speedup vs baseline: 1.0326x; 1.0326x over previous
//
#include <hip/hip_runtime.h>
#include <hip/hip_bf16.h>

// R11 = R9 (best, 128.5us) + two attn micro-opts:
//  (1) vg slab re-permuted so dt-pairs are contiguous 16B -> V LDS reads are b128
//      conflict-free (was b64 at 4-way conflict).
//  (2) packed f32->bf16 via __float22bfloat162_rn (v_cvt_pk_bf16_f32, RNE --
//      bit-identical to scalar f2bf) for the P fragment.
// Structure: cvt(x,wq,wp->bf16) -> gemm<0,256>@512thr (DMA dbuf, operand-order K/V slabs)
//            -> attn@768x256 (DMA dbuf, XCD slab swizzle, S^T trick + mfma16 PV)
//            -> gemm<1,128>@256thr (proj -> fp32).
// ws (ushort): qg | kg | vg | aout | xb | wqb | wpb = 32.5 MB.

typedef __attribute__((__ext_vector_type__(8))) __bf16 bf16x8;
typedef __attribute__((__ext_vector_type__(8))) unsigned short ushort8;
typedef __attribute__((__ext_vector_type__(4))) unsigned short ushort4v;
typedef __attribute__((__ext_vector_type__(4))) short short4v;
typedef __attribute__((__ext_vector_type__(4))) float f32x4;

#define NX 3145728   // 8192*384
#define NQ 442368    // 1152*384

__device__ __forceinline__ f32x4 mfma32(bf16x8 a, bf16x8 b, f32x4 c) {
    return __builtin_amdgcn_mfma_f32_16x16x32_bf16(a, b, c, 0, 0, 0);
}
__device__ __forceinline__ f32x4 mfma16(short4v a, short4v b, f32x4 c) {
    return __builtin_amdgcn_mfma_f32_16x16x16bf16_1k(a, b, c, 0, 0, 0);
}

__device__ __forceinline__ unsigned short f2bf(float f) {
    union { float f; unsigned int i; } x; x.f = f;
    unsigned int u = x.i;
    return (unsigned short)((u + 0x7fffu + ((u >> 16) & 1u)) >> 16);
}

__device__ __forceinline__ void dma16(const unsigned short* g, unsigned short* l) {
    __builtin_amdgcn_global_load_lds(
        (const __attribute__((address_space(1))) unsigned int*)g,
        (__attribute__((address_space(3))) unsigned int*)l, 16, 0, 0);
}

// fp32 -> bf16 for x, w_qkv, w_proj. 4 elems/thread.
__global__ __launch_bounds__(256) void cvt_bf16(
    const float* __restrict__ x, const float* __restrict__ wq, const float* __restrict__ wp,
    unsigned short* __restrict__ xb, unsigned short* __restrict__ wqb, unsigned short* __restrict__ wpb)
{
    int i = blockIdx.x * 256 + threadIdx.x;
    const float* src; unsigned short* dst; int off;
    if (i < NX / 4)              { src = x;  dst = xb;  off = i * 4; }
    else if (i < (NX + NQ) / 4)  { src = wq; dst = wqb; off = i * 4 - NX; }
    else                         { src = wp; dst = wpb; off = i * 4 - NX - NQ; }
    float4 v = *(const float4*)(src + off);
    ushort4v r;
    r[0] = f2bf(v.x); r[1] = f2bf(v.y); r[2] = f2bf(v.z); r[3] = f2bf(v.w);
    *(ushort4v*)(dst + off) = r;
}

// C = A[M,K] @ B[N,K]^T + bias. bf16 in, fp32 acc, TMx128 tile, BK=32, THREADS=2*TM.
// Single-barrier double-buffered DMA pipeline.
// MODE 0 (QKV): n<384 -> qg row-major *0.125 ; 384..768 -> kg operand-order ; >=768 -> vg.
//   kg slab (b,h) [64 kt][2 half][4 quad][16 l15][8 j]: K[kv=kt*16+l15][c=half*32+quad*8+j]
//   vg slab (b,h) [16 c][8 jp][4 quad][16 lv][2 dti][4 j]: jp = jt*2+(dt>>1), dti = dt&1;
//     V^T[d=dt*16+lv][kv=c*64+jt*16+quad*4+j]  (dt-pairs contiguous -> b128 attn reads)
// MODE 1 (proj): fp32 out + bias.
template <int MODE, int TM>
__global__ __launch_bounds__(TM * 2) void gemm_bt(
    const unsigned short* __restrict__ A,
    const unsigned short* __restrict__ B,
    const float* __restrict__ bias,
    unsigned short* __restrict__ qg,
    unsigned short* __restrict__ kg,
    unsigned short* __restrict__ vg,
    float* __restrict__ out,
    int M, int N, int K)
{
    const int tid  = threadIdx.x;
    const int lane = tid & 63;
    const int wave = tid >> 6;
    const int l15  = lane & 15;
    const int quad = lane >> 4;
    const int m0 = blockIdx.x * TM;
    const int n0 = blockIdx.y * 128;
    const int wm = (wave >> 1) * 64;
    const int wn = (wave & 1) * 64;

    __shared__ __align__(16) unsigned short As[2 * TM * 32];
    __shared__ __align__(16) unsigned short Bs[2 * 128 * 32];

    f32x4 acc[4][4];
    #pragma unroll
    for (int i = 0; i < 4; ++i)
        #pragma unroll
        for (int j = 0; j < 4; ++j)
            acc[i][j] = (f32x4){0.f, 0.f, 0.f, 0.f};

    auto stage = [&](int k0, int buf) {
        #pragma unroll
        for (int t = 0; t < 2; ++t) {
            int i = tid + t * TM * 2;
            dma16(A + (size_t)(m0 + (i >> 2)) * K + k0 + (i & 3) * 8,
                  As + buf * TM * 32 + t * TM * 16 + wave * 512);
        }
        #pragma unroll
        for (int t = 0; t < 512 / (TM * 2); ++t) {
            int i = tid + t * TM * 2;
            dma16(B + (size_t)(n0 + (i >> 2)) * K + k0 + (i & 3) * 8,
                  Bs + buf * 4096 + t * TM * 16 + wave * 512);
        }
    };

    const int nk = K >> 5;   // 12
    stage(0, 0);
    for (int ki = 0; ki < nk; ++ki) {
        __syncthreads();                       // drains DMA for buf ki&1; syncs compute ki-1
        if (ki + 1 < nk) stage((ki + 1) << 5, (ki + 1) & 1);
        const unsigned short* as = As + (ki & 1) * TM * 32;
        const unsigned short* bs = Bs + (ki & 1) * 4096;

        bf16x8 af[4], bff[4];
        #pragma unroll
        for (int mt = 0; mt < 4; ++mt)
            af[mt] = *(const bf16x8*)(as + (wm + mt * 16 + l15) * 32 + quad * 8);
        #pragma unroll
        for (int nt = 0; nt < 4; ++nt)
            bff[nt] = *(const bf16x8*)(bs + (wn + nt * 16 + l15) * 32 + quad * 8);
        #pragma unroll
        for (int mt = 0; mt < 4; ++mt)
            #pragma unroll
            for (int nt = 0; nt < 4; ++nt)
                acc[mt][nt] = mfma32(af[mt], bff[nt], acc[mt][nt]);
    }

    if constexpr (MODE == 0) {
        if (n0 < 384) {            // Q region: row-major, pre-scaled
            #pragma unroll
            for (int nt = 0; nt < 4; ++nt) {
                int n = n0 + wn + nt * 16 + l15;
                float bv = bias[n];
                #pragma unroll
                for (int mt = 0; mt < 4; ++mt) {
                    int mbase = m0 + wm + mt * 16 + quad * 4;
                    #pragma unroll
                    for (int r = 0; r < 4; ++r)
                        qg[(size_t)(mbase + r) * 384 + n] = f2bf((acc[mt][nt][r] + bv) * 0.125f);
                }
            }
        } else if (n0 < 768) {     // K region: operand-order slabs
            #pragma unroll
            for (int nt = 0; nt < 4; ++nt) {
                int n = n0 + wn + nt * 16 + l15;
                float bv = bias[n];
                int c2 = n - 384;
                int h = c2 >> 6, ck = c2 & 63;
                int half = ck >> 5, qd = (ck >> 3) & 3, j = ck & 7;
                #pragma unroll
                for (int mt = 0; mt < 4; ++mt) {
                    int mbase = m0 + wm + mt * 16 + quad * 4;
                    #pragma unroll
                    for (int r = 0; r < 4; ++r) {
                        int tok = mbase + r;
                        int b = tok >> 10, kv = tok & 1023;
                        int kt = kv >> 4, lk = kv & 15;
                        kg[(size_t)(b * 6 + h) * 65536 +
                           ((((size_t)kt * 2 + half) * 4 + qd) * 16 + lk) * 8 + j]
                            = f2bf(acc[mt][nt][r] + bv);
                    }
                }
            }
        } else {                   // V region: dt-paired operand-order slabs
            #pragma unroll
            for (int nt = 0; nt < 4; ++nt) {
                int n = n0 + wn + nt * 16 + l15;
                float bv = bias[n];
                int c2 = n - 768;
                int h = c2 >> 6, d = c2 & 63;
                int dt = d >> 4, lv = d & 15;
                #pragma unroll
                for (int mt = 0; mt < 4; ++mt) {
                    int mbase = m0 + wm + mt * 16 + quad * 4;   // multiple of 4
                    int b = mbase >> 10, kvb = mbase & 1023;
                    int cc = kvb >> 6, jt = (kvb >> 4) & 3, qd = (kvb >> 2) & 3;
                    ushort4v pk;
                    #pragma unroll
                    for (int r = 0; r < 4; ++r) pk[r] = f2bf(acc[mt][nt][r] + bv);
                    *(ushort4v*)(vg + (size_t)(b * 6 + h) * 65536 + (size_t)cc * 4096 +
                                 ((((jt * 2 + (dt >> 1)) * 4 + qd) * 16 + lv) * 2 + (dt & 1)) * 4)
                        = pk;
                }
            }
        }
    } else {
        #pragma unroll
        for (int nt = 0; nt < 4; ++nt) {
            int n = n0 + wn + nt * 16 + l15;
            float bv = bias[n];
            #pragma unroll
            for (int mt = 0; mt < 4; ++mt) {
                int mbase = m0 + wm + mt * 16 + quad * 4;
                #pragma unroll
                for (int r = 0; r < 4; ++r)
                    out[(size_t)(mbase + r) * N + n] = acc[mt][nt][r] + bv;
            }
        }
    }
}

// Flash attention, dbuf LDS pipeline + XCD-locality swizzle.
// Per kt: 2 b128 K reads, 2 mfma32 (S^T), mask+exp, packed cvt, 2 b128 V-pair reads,
// 4 mfma16 (PV). Lane mappings validated R5/R7.
__global__ __launch_bounds__(256) void attn_fused(
    const unsigned short* __restrict__ qg,
    const unsigned short* __restrict__ kg,
    const unsigned short* __restrict__ vg,
    unsigned short* __restrict__ aout)   // [8192][384] bf16
{
    const int tid  = threadIdx.x;
    const int wave = tid >> 6;
    const int lane = tid & 63;
    const int l15  = lane & 15;
    const int quad = lane >> 4;
    const int id = blockIdx.x;
    const int s  = id % 48;      // slab = b*6+h (pins slab to one XCD: id%8 == s%8)
    const int qt = id / 48;      // 0..15
    const int b  = s / 6;
    const int h  = s % 6;

    const size_t rowbase = (size_t)b * 1024;
    const unsigned short* Kslab = kg + (size_t)s * 65536;
    const unsigned short* Vslab = vg + (size_t)s * 65536;
    const int q0 = qt * 64 + wave * 16;

    __shared__ __align__(16) unsigned short Kb[2 * 4096];
    __shared__ __align__(16) unsigned short Vb[2 * 4096];

    bf16x8 aq0, aq1;
    {
        const unsigned short* qrow = qg + (rowbase + q0 + l15) * 384 + h * 64 + quad * 8;
        aq0 = *(const bf16x8*)qrow;
        aq1 = *(const bf16x8*)(qrow + 32);
    }

    f32x4 accO[4];
    #pragma unroll
    for (int dt = 0; dt < 4; ++dt) accO[dt] = (f32x4){0.f, 0.f, 0.f, 0.f};
    float lsum = 0.f;

    auto stage = [&](int c, int buf) {
        #pragma unroll
        for (int t = 0; t < 2; ++t) {
            int i = tid + t * 256;
            dma16(Kslab + (size_t)c * 4096 + i * 8, Kb + buf * 4096 + t * 2048 + wave * 512);
            dma16(Vslab + (size_t)c * 4096 + i * 8, Vb + buf * 4096 + t * 2048 + wave * 512);
        }
    };

    stage(0, 0);
    for (int c = 0; c < 16; ++c) {
        __syncthreads();                          // drains chunk c's DMA; syncs compute c-1
        if (c + 1 < 16) stage(c + 1, (c + 1) & 1);   // in flight during compute of c
        const unsigned short* kb = Kb + (c & 1) * 4096;
        const unsigned short* vb = Vb + (c & 1) * 4096;

        #pragma unroll
        for (int kt = 0; kt < 4; ++kt) {
            bf16x8 ka  = *(const bf16x8*)(kb + (((kt * 2 + 0) * 4 + quad) * 16 + l15) * 8);
            bf16x8 kbf = *(const bf16x8*)(kb + (((kt * 2 + 1) * 4 + quad) * 16 + l15) * 8);
            f32x4 z = (f32x4){0.f, 0.f, 0.f, 0.f};
            z = mfma32(ka, aq0, z);
            z = mfma32(kbf, aq1, z);   // S^T[kv=quad*4+r][q=l15]

            float e[4];
            #pragma unroll
            for (int r = 0; r < 4; ++r) {
                float sc = z[r];
                sc = (sc < 0.f) ? 0.f : __expf(sc);   // threshold mask -> exact 0 (matches ref)
                lsum += sc;
                e[r] = sc;
            }
            union { __hip_bfloat162 h2[2]; short4v v; } pu;
            pu.h2[0] = __float22bfloat162_rn(float2{e[0], e[1]});   // v_cvt_pk_bf16_f32 (RNE)
            pu.h2[1] = __float22bfloat162_rn(float2{e[2], e[3]});
            short4v p = pu.v;

            #pragma unroll
            for (int dtp = 0; dtp < 2; ++dtp) {
                union { bf16x8 w; short4v s4[2]; } vv;
                vv.w = *(const bf16x8*)(vb + (((kt * 2 + dtp) * 4 + quad) * 16 + l15) * 8);
                accO[dtp * 2 + 0] = mfma16(vv.s4[0], p, accO[dtp * 2 + 0]);
                accO[dtp * 2 + 1] = mfma16(vv.s4[1], p, accO[dtp * 2 + 1]);
            }
        }
    }

    lsum += __shfl_xor(lsum, 16, 64);
    lsum += __shfl_xor(lsum, 32, 64);
    float inv = 1.0f / lsum;

    unsigned short* orow = aout + (rowbase + q0 + l15) * 384 + h * 64 + quad * 4;
    #pragma unroll
    for (int dt = 0; dt < 4; ++dt) {
        ushort4v pk;
        #pragma unroll
        for (int r = 0; r < 4; ++r) pk[r] = f2bf(accO[dt][r] * inv);
        *(ushort4v*)(orow + dt * 16) = pk;
    }
}

extern "C" void kernel_launch(void* const* d_in, const int* in_sizes, int n_in,
                              void* d_out, int out_size, void* d_ws, size_t ws_size,
                              hipStream_t stream) {
    const float* x      = (const float*)d_in[0];  // [8,1024,384]
    const float* w_qkv  = (const float*)d_in[1];  // [1152,384]
    const float* b_qkv  = (const float*)d_in[2];  // [1152]
    const float* w_proj = (const float*)d_in[3];  // [384,384]
    const float* b_proj = (const float*)d_in[4];  // [384]
    float* out = (float*)d_out;                   // [8,1024,384]

    unsigned short* qg   = (unsigned short*)d_ws;            // 8192*384
    unsigned short* kgp  = qg   + (size_t)NX;                // 48*65536
    unsigned short* vgp  = kgp  + (size_t)NX;                // 48*65536
    unsigned short* aout = vgp  + (size_t)NX;                // 8192*384
    unsigned short* xb   = aout + (size_t)NX;                // 8192*384
    unsigned short* wqb  = xb   + (size_t)NX;                // 1152*384
    unsigned short* wpb  = wqb  + (size_t)NQ;                // 384*384

    cvt_bf16<<<3648, 256, 0, stream>>>(x, w_qkv, w_proj, xb, wqb, wpb);
    gemm_bt<0, 256><<<dim3(32, 9), 512, 0, stream>>>(
        xb, wqb, b_qkv, qg, kgp, vgp, nullptr, 8192, 1152, 384);
    attn_fused<<<768, 256, 0, stream>>>(qg, kgp, vgp, aout);
    gemm_bt<1, 128><<<dim3(64, 3), 256, 0, stream>>>(
        aout, wpb, b_proj, nullptr, nullptr, nullptr, out, 8192, 384, 384);
}